// Round 6
// baseline (134.717 us; speedup 1.0000x reference)
//
#include <hip/hip_runtime.h>

#define M_COLS 2048
#define KOUT 64
#define CAND 128
#define BLK 256  // 4 waves/block, 1 row/wave

typedef unsigned long long u64;

// ---- DPP move (pure VALU): quad_perm / row_shr / row_bcast
#define DPPU(old, src, ctrl, rmask) \
  ((unsigned)__builtin_amdgcn_update_dpp((int)(old), (int)(src), (ctrl), (rmask), 0xF, false))
#define RDL(x, l) ((unsigned)__builtin_amdgcn_readlane((int)(x), (l)))

// canonical wave64 inclusive scans: row_shr 1/2/4/8, bcast15 (rows 1,3), bcast31 (rows 2,3)
#define SCAN_ADD_U(x)             \
  do {                            \
    x += DPPU(0u, x, 0x111, 0xF); \
    x += DPPU(0u, x, 0x112, 0xF); \
    x += DPPU(0u, x, 0x114, 0xF); \
    x += DPPU(0u, x, 0x118, 0xF); \
    x += DPPU(0u, x, 0x142, 0xA); \
    x += DPPU(0u, x, 0x143, 0xC); \
  } while (0)

#define SCAN_MAX_U(x)                                  \
  do {                                                 \
    unsigned _t;                                       \
    _t = DPPU(0u, x, 0x111, 0xF); x = x > _t ? x : _t; \
    _t = DPPU(0u, x, 0x112, 0xF); x = x > _t ? x : _t; \
    _t = DPPU(0u, x, 0x114, 0xF); x = x > _t ? x : _t; \
    _t = DPPU(0u, x, 0x118, 0xF); x = x > _t ? x : _t; \
    _t = DPPU(0u, x, 0x142, 0xA); x = x > _t ? x : _t; \
    _t = DPPU(0u, x, 0x143, 0xC); x = x > _t ? x : _t; \
  } while (0)

#define SCAN_ADD_F(x)                                               \
  do {                                                              \
    x += __uint_as_float(DPPU(0u, __float_as_uint(x), 0x111, 0xF)); \
    x += __uint_as_float(DPPU(0u, __float_as_uint(x), 0x112, 0xF)); \
    x += __uint_as_float(DPPU(0u, __float_as_uint(x), 0x114, 0xF)); \
    x += __uint_as_float(DPPU(0u, __float_as_uint(x), 0x118, 0xF)); \
    x += __uint_as_float(DPPU(0u, __float_as_uint(x), 0x142, 0xA)); \
    x += __uint_as_float(DPPU(0u, __float_as_uint(x), 0x143, 0xC)); \
  } while (0)

// xor-lane exchange within 32-lane halves via ds_swizzle (BitMode: (xor<<10)|0x1f)
#define SWZ(v, J) ((unsigned)__builtin_amdgcn_ds_swizzle((int)(v), (((J) << 10) | 0x1f)))

// u64 partner fetch: ds_swizzle (J=4,8,16), DPP quad_perm (J=1,2), bpermute (J=32)
#define EX_S(dst, src, J)                           \
  do {                                              \
    unsigned _lo = SWZ((unsigned)(src), J);         \
    unsigned _hi = SWZ((unsigned)((src) >> 32), J); \
    dst = ((u64)_hi << 32) | _lo;                   \
  } while (0)
#define EX_D(dst, src, CTRL)                                     \
  do {                                                           \
    unsigned _lo = DPPU(0u, (unsigned)(src), CTRL, 0xF);         \
    unsigned _hi = DPPU(0u, (unsigned)((src) >> 32), CTRL, 0xF); \
    dst = ((u64)_hi << 32) | _lo;                                \
  } while (0)
#define EX_W(dst, src)                                                         \
  do {                                                                         \
    unsigned _lo = (unsigned)__shfl_xor((int)(unsigned)(src), 32, 64);         \
    unsigned _hi = (unsigned)__shfl_xor((int)(unsigned)((src) >> 32), 32, 64); \
    dst = ((u64)_hi << 32) | _lo;                                              \
  } while (0)

// dual compare-exchange: k0 descending, k1 ascending (mirrored)
#define CMPSEL(up)                       \
  do {                                   \
    k0 = ((k0 >= o0) == (up)) ? k0 : o0; \
    k1 = ((k1 >= o1) == (up)) ? o1 : k1; \
  } while (0)

#define STEP_A_S(J, UP) do { u64 o0, o1; EX_S(o0, k0, J); EX_S(o1, k1, J); CMPSEL(UP); } while (0)
#define STEP_A_D(CTRL, UP) do { u64 o0, o1; EX_D(o0, k0, CTRL); EX_D(o1, k1, CTRL); CMPSEL(UP); } while (0)
#define STEP_A_W(UP) do { u64 o0, o1; EX_W(o0, k0); EX_W(o1, k1); CMPSEL(UP); } while (0)

// descending bitonic merge stage on av
#define STEP_B_S(J, UP) do { u64 o; EX_S(o, av, J); av = ((av >= o) == (UP)) ? av : o; } while (0)
#define STEP_B_D(CTRL, UP) do { u64 o; EX_D(o, av, CTRL); av = ((av >= o) == (UP)) ? av : o; } while (0)
#define STEP_B_W(UP) do { u64 o; EX_W(o, av); av = ((av >= o) == (UP)) ? av : o; } while (0)

__global__ __launch_bounds__(BLK, 8) void topk_route_kernel(
    const float* __restrict__ A, const int* __restrict__ topk,
    float* __restrict__ out_w, float* __restrict__ out_i, int NQ, int Q, int N) {
  __shared__ u64 cand[4][CAND];

  const unsigned tid = threadIdx.x;
  const unsigned wv = tid >> 6, lane = tid & 63u;
  const unsigned row = blockIdx.x * 4u + wv;
  if ((int)row >= NQ) return;
  const unsigned n = row / (unsigned)Q;

  // ---- load + mask fused (compiler reuses load dest regs as bits: low VGPR)
  const float4* a4 = (const float4*)(A + (size_t)row * M_COLS);
  unsigned bits[32];
#pragma unroll
  for (int t = 0; t < 8; ++t) {
    float4 vv = a4[lane + 64u * (unsigned)t];
    bits[4 * t + 0] = __float_as_uint(vv.x) & 0x7fffffffu;
    bits[4 * t + 1] = __float_as_uint(vv.y) & 0x7fffffffu;
    bits[4 * t + 2] = __float_as_uint(vv.z) & 0x7fffffffu;
    bits[4 * t + 3] = __float_as_uint(vv.w) & 0x7fffffffu;
  }

  // zero pad slots of the upper half (lower 64 always overwritten: csel >= 64)
  cand[wv][lane + 64u] = 0ull;

  // ---- branch-free topk sniff (int64 vs int32; uniform address -> scalar loads)
  int kk;
  if (N >= 8) {
    const int4* t4 = (const int4*)topk;
    int4 a = t4[0], b = t4[1], c = t4[2], d = t4[3];
    int k64 = topk[2 * (int)n], k32 = topk[(int)n];
    bool looks64 = (a.y == 0) & (a.w == 0) & (b.y == 0) & (b.w == 0) &
                   (c.y == 0) & (c.w == 0) & (d.y == 0) & (d.w == 0) &
                   (a.x >= 1) & (a.z >= 1) & (b.x >= 1) & (b.z >= 1) &
                   (c.x >= 1) & (c.z >= 1) & (d.x >= 1) & (d.z >= 1);
    kk = looks64 ? k64 : k32;
  } else {
    bool looks64 = true;
    for (int i = 0; i < N; ++i) {
      int l = topk[2 * i], h = topk[2 * i + 1];
      if (h != 0 || l < 1) { looks64 = false; break; }
    }
    kk = looks64 ? topk[2 * (int)n] : topk[(int)n];
  }
  kk = kk > M_COLS ? M_COLS : (kk < 0 ? 0 : kk);

  // ---- wave max -> uniform em
  unsigned mx = bits[0];
#pragma unroll
  for (int j = 1; j < 32; ++j) mx = bits[j] > mx ? bits[j] : mx;
  SCAN_MAX_U(mx);
  mx = RDL(mx, 63);
  const int em = (int)(mx >> 23);

  // attempt(T): per-lane keep-mask (VALU) + wave count via ballot (scalar pipe)
  unsigned keep = 0u, csel = 0u;
  auto attempt = [&](unsigned T) {
    unsigned q0 = 0u, q1 = 0u, q2 = 0u, q3 = 0u, c = 0u;
#pragma unroll
    for (int j = 7; j >= 0; --j) {
      bool p0 = bits[j] >= T, p1 = bits[8 + j] >= T;
      bool p2 = bits[16 + j] >= T, p3 = bits[24 + j] >= T;
      q0 = q0 + q0 + (unsigned)p0;
      q1 = q1 + q1 + (unsigned)p1;
      q2 = q2 + q2 + (unsigned)p2;
      q3 = q3 + q3 + (unsigned)p3;
      c += (unsigned)__popcll(__ballot(p0)) + (unsigned)__popcll(__ballot(p1)) +
           (unsigned)__popcll(__ballot(p2)) + (unsigned)__popcll(__ballot(p3));
    }
    keep = q0 | (q1 << 8) | (q2 << 16) | (q3 << 24);
    csel = c;  // wave-uniform
  };

  // ---- probe em, em-1, em-2 (T=0 always qualifies: count=2048)
  unsigned lo, hi = mx + 1u;
  {
    unsigned T = (em > 0) ? ((unsigned)em << 23) : 0u;
    attempt(T); lo = T;
    if (csel < KOUT) {
      hi = T;
      T = (em - 1 > 0) ? ((unsigned)(em - 1) << 23) : 0u;
      attempt(T); lo = T;
      if (csel < KOUT) {
        hi = T;
        T = (em - 2 > 0) ? ((unsigned)(em - 2) << 23) : 0u;
        attempt(T); lo = T;
        if (csel < KOUT) { hi = T; attempt(0u); lo = 0u; }
      }
    }
  }

  // ---- rare: binary refine until 64 <= count(>=lo) <= 128
  {
    unsigned csel_lo = csel, lastT = lo;
    while (csel_lo > CAND && lo + 1u < hi) {
      unsigned mid = lo + ((hi - lo) >> 1);
      attempt(mid); lastT = mid;
      if (csel >= KOUT) { lo = mid; csel_lo = csel; } else hi = mid;
    }
    if (lastT != lo) attempt(lo);
  }

  // ---- ultra-rare: >128 ties at lo: keep all > lo + smallest-index ties
  if (csel > CAND) {
    unsigned kgt = 0u, cgt = 0u;
#pragma unroll
    for (int j = 31; j >= 0; --j) {
      bool pg = bits[j] >= hi;
      kgt = (kgt << 1) | (unsigned)pg;
      cgt += (unsigned)__popcll(__ballot(pg));
    }
    unsigned cap = CAND - cgt;
    keep = kgt;
    unsigned run = 0u;
#pragma unroll
    for (int t = 0; t < 8; ++t) {
      unsigned f = 0u;
#pragma unroll
      for (int c = 3; c >= 0; --c) f = (f << 1) | (unsigned)(bits[4 * t + c] == lo);
      unsigned tc = __popc(f), it = tc;
      SCAN_ADD_U(it);
      unsigned tbase = run + it - tc;
#pragma unroll
      for (int c = 0; c < 4; ++c) {
        if (f & (1u << c)) {
          if (tbase < cap) keep |= 1u << (4 * t + c);
          ++tbase;
        }
      }
      run += RDL(it, 63);
    }
  }

  // ---- compaction: one DPP scan for the base, popc-indexed independent stores
  unsigned sl = __popc(keep);
  unsigned inc = sl;
  SCAN_ADD_U(inc);
  unsigned base = inc - sl;  // exclusive prefix = write base
  const unsigned lobase = 2047u - 4u * lane;
  u64* cw = &cand[wv][0];
#pragma unroll
  for (int j = 0; j < 32; ++j) {
    if (keep & (1u << j)) {
      unsigned pj = base + (unsigned)__popc(keep & ((1u << j) - 1u));
      cw[pj] = ((u64)bits[j] << 32) |
               (u64)(lobase - (unsigned)((j >> 2) * 256 + (j & 3)));
    }
  }

  // ---- per-stage comparator flags from lane bits
  const bool b1 = (lane & 1u) != 0u, b2 = (lane & 2u) != 0u, b4 = (lane & 4u) != 0u;
  const bool b8 = (lane & 8u) != 0u, b16 = (lane & 16u) != 0u, b32 = (lane & 32u) != 0u;

  // ---- sort: k0 desc + k1 asc (21 dual stages), local exchange, merge top half
  u64 k0 = cand[wv][lane];
  u64 k1 = cand[wv][lane + 64u];
  // k=2
  STEP_A_D(0xB1, !(b2 ^ b1));
  // k=4
  STEP_A_D(0x4E, !(b4 ^ b2)); STEP_A_D(0xB1, !(b4 ^ b1));
  // k=8
  STEP_A_S(4, !(b8 ^ b4)); STEP_A_D(0x4E, !(b8 ^ b2)); STEP_A_D(0xB1, !(b8 ^ b1));
  // k=16
  STEP_A_S(8, !(b16 ^ b8)); STEP_A_S(4, !(b16 ^ b4));
  STEP_A_D(0x4E, !(b16 ^ b2)); STEP_A_D(0xB1, !(b16 ^ b1));
  // k=32
  STEP_A_S(16, !(b32 ^ b16)); STEP_A_S(8, !(b32 ^ b8)); STEP_A_S(4, !(b32 ^ b4));
  STEP_A_D(0x4E, !(b32 ^ b2)); STEP_A_D(0xB1, !(b32 ^ b1));
  // k=64 (lane&64 == 0 always)
  STEP_A_W(!b32);
  STEP_A_S(16, !b16); STEP_A_S(8, !b8); STEP_A_S(4, !b4);
  STEP_A_D(0x4E, !b2); STEP_A_D(0xB1, !b1);

  u64 av = k0 >= k1 ? k0 : k1;  // bitonic; holds the top-64 set
  STEP_B_W(!b32);
  STEP_B_S(16, !b16); STEP_B_S(8, !b8); STEP_B_S(4, !b4);
  STEP_B_D(0x4E, !b2); STEP_B_D(0xB1, !b1);

  // ---- softmax over first kk entries; lane = rank (sorted desc)
  float val = __uint_as_float((unsigned)(av >> 32));
  unsigned midx = 2047u - (unsigned)(av & 0xffffffffull);
  bool valid = (int)lane < kk;

  float vmx = __uint_as_float(
      (unsigned)__builtin_amdgcn_readfirstlane((int)(unsigned)(av >> 32)));
  float e = valid ? __expf(val - vmx) : 0.0f;
  float s = e;
  SCAN_ADD_F(s);
  float stot = __uint_as_float(RDL(__float_as_uint(s), 63));
  float w = valid ? (e / stot) : 0.0f;

  size_t o = (size_t)row * KOUT + lane;
  out_w[o] = w;
  out_i[o] = valid ? (float)midx : 0.0f;
}

extern "C" void kernel_launch(void* const* d_in, const int* in_sizes, int n_in,
                              void* d_out, int out_size, void* d_ws, size_t ws_size,
                              hipStream_t stream) {
  const float* A = (const float*)d_in[0];
  const int* topk = (const int*)d_in[1];
  float* out = (float*)d_out;
  const int NQ = in_sizes[0] / M_COLS;
  const int N = in_sizes[1] > 0 ? in_sizes[1] : 1;
  const int Q = NQ / N;
  float* out_w = out;
  float* out_i = out + (size_t)NQ * KOUT;
  const int blocks = (NQ + 3) / 4;
  hipLaunchKernelGGL(topk_route_kernel, dim3(blocks), dim3(BLK), 0, stream, A,
                     topk, out_w, out_i, NQ, Q, N);
}

// Round 7
// 39.576 us; speedup vs baseline: 3.4040x; 3.4040x over previous
//
#include <hip/hip_runtime.h>

#define M_COLS 2048
#define KOUT 64
#define CAND 128
#define BLK 256   // 4 waves/block, 1 row/wave iteration
#define ROWS 4    // rows per wave, software-pipelined

typedef unsigned long long u64;

// ---- DPP move (pure VALU): quad_perm / row_shr / row_bcast
#define DPPU(old, src, ctrl, rmask) \
  ((unsigned)__builtin_amdgcn_update_dpp((int)(old), (int)(src), (ctrl), (rmask), 0xF, false))
#define RDL(x, l) ((unsigned)__builtin_amdgcn_readlane((int)(x), (l)))

// canonical wave64 inclusive scans: row_shr 1/2/4/8, bcast15 (rows 1,3), bcast31 (rows 2,3)
#define SCAN_ADD_U(x)             \
  do {                            \
    x += DPPU(0u, x, 0x111, 0xF); \
    x += DPPU(0u, x, 0x112, 0xF); \
    x += DPPU(0u, x, 0x114, 0xF); \
    x += DPPU(0u, x, 0x118, 0xF); \
    x += DPPU(0u, x, 0x142, 0xA); \
    x += DPPU(0u, x, 0x143, 0xC); \
  } while (0)

#define SCAN_MAX_U(x)                                  \
  do {                                                 \
    unsigned _t;                                       \
    _t = DPPU(0u, x, 0x111, 0xF); x = x > _t ? x : _t; \
    _t = DPPU(0u, x, 0x112, 0xF); x = x > _t ? x : _t; \
    _t = DPPU(0u, x, 0x114, 0xF); x = x > _t ? x : _t; \
    _t = DPPU(0u, x, 0x118, 0xF); x = x > _t ? x : _t; \
    _t = DPPU(0u, x, 0x142, 0xA); x = x > _t ? x : _t; \
    _t = DPPU(0u, x, 0x143, 0xC); x = x > _t ? x : _t; \
  } while (0)

#define SCAN_ADD_F(x)                                               \
  do {                                                              \
    x += __uint_as_float(DPPU(0u, __float_as_uint(x), 0x111, 0xF)); \
    x += __uint_as_float(DPPU(0u, __float_as_uint(x), 0x112, 0xF)); \
    x += __uint_as_float(DPPU(0u, __float_as_uint(x), 0x114, 0xF)); \
    x += __uint_as_float(DPPU(0u, __float_as_uint(x), 0x118, 0xF)); \
    x += __uint_as_float(DPPU(0u, __float_as_uint(x), 0x142, 0xA)); \
    x += __uint_as_float(DPPU(0u, __float_as_uint(x), 0x143, 0xC)); \
  } while (0)

// xor-lane exchange within 32-lane halves via ds_swizzle (BitMode: (xor<<10)|0x1f)
#define SWZ(v, J) ((unsigned)__builtin_amdgcn_ds_swizzle((int)(v), (((J) << 10) | 0x1f)))

// u64 partner fetch: ds_swizzle (J=4,8,16), DPP quad_perm (J=1,2), bpermute (J=32)
#define EX_S(dst, src, J)                           \
  do {                                              \
    unsigned _lo = SWZ((unsigned)(src), J);         \
    unsigned _hi = SWZ((unsigned)((src) >> 32), J); \
    dst = ((u64)_hi << 32) | _lo;                   \
  } while (0)
#define EX_D(dst, src, CTRL)                                     \
  do {                                                           \
    unsigned _lo = DPPU(0u, (unsigned)(src), CTRL, 0xF);         \
    unsigned _hi = DPPU(0u, (unsigned)((src) >> 32), CTRL, 0xF); \
    dst = ((u64)_hi << 32) | _lo;                                \
  } while (0)
#define EX_W(dst, src)                                                         \
  do {                                                                         \
    unsigned _lo = (unsigned)__shfl_xor((int)(unsigned)(src), 32, 64);         \
    unsigned _hi = (unsigned)__shfl_xor((int)(unsigned)((src) >> 32), 32, 64); \
    dst = ((u64)_hi << 32) | _lo;                                              \
  } while (0)

// dual compare-exchange: k0 descending, k1 ascending (mirrored)
#define CMPSEL(up)                       \
  do {                                   \
    k0 = ((k0 >= o0) == (up)) ? k0 : o0; \
    k1 = ((k1 >= o1) == (up)) ? o1 : k1; \
  } while (0)

#define STEP_A_S(J, UP) do { u64 o0, o1; EX_S(o0, k0, J); EX_S(o1, k1, J); CMPSEL(UP); } while (0)
#define STEP_A_D(CTRL, UP) do { u64 o0, o1; EX_D(o0, k0, CTRL); EX_D(o1, k1, CTRL); CMPSEL(UP); } while (0)
#define STEP_A_W(UP) do { u64 o0, o1; EX_W(o0, k0); EX_W(o1, k1); CMPSEL(UP); } while (0)

// descending bitonic merge stage on av
#define STEP_B_S(J, UP) do { u64 o; EX_S(o, av, J); av = ((av >= o) == (UP)) ? av : o; } while (0)
#define STEP_B_D(CTRL, UP) do { u64 o; EX_D(o, av, CTRL); av = ((av >= o) == (UP)) ? av : o; } while (0)
#define STEP_B_W(UP) do { u64 o; EX_W(o, av); av = ((av >= o) == (UP)) ? av : o; } while (0)

__global__ __launch_bounds__(BLK) void topk_route_kernel(
    const float* __restrict__ A, const int* __restrict__ topk,
    float* __restrict__ out_w, float* __restrict__ out_i, int NQ, int Q, int N) {
  __shared__ u64 cand[4][CAND];

  const unsigned tid = threadIdx.x;
  const unsigned wv = tid >> 6, lane = tid & 63u;
  const unsigned r0 = (blockIdx.x * 4u + wv) * ROWS;
  if ((int)r0 >= NQ) return;

  // ---- topk dtype sniff once (uniform; int64 vs int32 layout)
  bool looks64;
  if (N >= 8) {
    const int4* t4 = (const int4*)topk;
    int4 a = t4[0], b = t4[1], c = t4[2], d = t4[3];
    looks64 = (a.y == 0) & (a.w == 0) & (b.y == 0) & (b.w == 0) &
              (c.y == 0) & (c.w == 0) & (d.y == 0) & (d.w == 0) &
              (a.x >= 1) & (a.z >= 1) & (b.x >= 1) & (b.z >= 1) &
              (c.x >= 1) & (c.z >= 1) & (d.x >= 1) & (d.z >= 1);
  } else {
    looks64 = true;
    for (int i = 0; i < N; ++i) {
      int l = topk[2 * i], h = topk[2 * i + 1];
      if (h != 0 || l < 1) { looks64 = false; break; }
    }
  }

  // ---- per-stage comparator flags from lane bits
  const bool b1 = (lane & 1u) != 0u, b2 = (lane & 2u) != 0u, b4 = (lane & 4u) != 0u;
  const bool b8 = (lane & 8u) != 0u, b16 = (lane & 16u) != 0u, b32 = (lane & 32u) != 0u;
  const unsigned lobase = 2047u - 4u * lane;
  u64* cw = &cand[wv][0];

  // ---- prefetch row r0
  float4 buf[8];
  {
    const float4* a4 = (const float4*)(A + (size_t)r0 * M_COLS);
#pragma unroll
    for (int t = 0; t < 8; ++t) buf[t] = a4[lane + 64u * (unsigned)t];
  }

  for (int i = 0; i < ROWS; ++i) {
    const unsigned row = r0 + (unsigned)i;
    if ((int)row >= NQ) break;

    // ---- consume prefetch buffer into sortable abs-bits
    unsigned bits[32];
#pragma unroll
    for (int t = 0; t < 8; ++t) {
      bits[4 * t + 0] = __float_as_uint(buf[t].x) & 0x7fffffffu;
      bits[4 * t + 1] = __float_as_uint(buf[t].y) & 0x7fffffffu;
      bits[4 * t + 2] = __float_as_uint(buf[t].z) & 0x7fffffffu;
      bits[4 * t + 3] = __float_as_uint(buf[t].w) & 0x7fffffffu;
    }

    // ---- issue next row's loads now; ~2000cy of compute below hides them
    if (i + 1 < ROWS && (int)(row + 1u) < NQ) {
      const float4* b4 = (const float4*)(A + (size_t)(row + 1u) * M_COLS);
#pragma unroll
      for (int t = 0; t < 8; ++t) buf[t] = b4[lane + 64u * (unsigned)t];
    }

    // zero pad slots of the upper half (lower 64 always overwritten: csel >= 64)
    cw[lane + 64u] = 0ull;

    // ---- wave max -> uniform em
    unsigned mx = bits[0];
#pragma unroll
    for (int j = 1; j < 32; ++j) mx = bits[j] > mx ? bits[j] : mx;
    SCAN_MAX_U(mx);
    mx = RDL(mx, 63);
    const int em = (int)(mx >> 23);

    // attempt(T): keep-mask (4 independent 8-chains) + popc + DPP scan + total
    unsigned keep = 0u, sl = 0u, inc = 0u, csel = 0u;
    auto attempt = [&](unsigned T) {
      unsigned q0 = 0u, q1 = 0u, q2 = 0u, q3 = 0u;
#pragma unroll
      for (int j = 7; j >= 0; --j) {
        q0 = q0 + q0 + (unsigned)(bits[j] >= T);
        q1 = q1 + q1 + (unsigned)(bits[8 + j] >= T);
        q2 = q2 + q2 + (unsigned)(bits[16 + j] >= T);
        q3 = q3 + q3 + (unsigned)(bits[24 + j] >= T);
      }
      keep = q0 | (q1 << 8) | (q2 << 16) | (q3 << 24);
      sl = __popc(keep);
      inc = sl;
      SCAN_ADD_U(inc);
      csel = RDL(inc, 63);
    };

    // ---- probe em, em-1, em-2 (T=0 always qualifies: count=2048)
    unsigned lo, hi = mx + 1u;
    {
      unsigned T = (em > 0) ? ((unsigned)em << 23) : 0u;
      attempt(T); lo = T;
      if (csel < KOUT) {
        hi = T;
        T = (em - 1 > 0) ? ((unsigned)(em - 1) << 23) : 0u;
        attempt(T); lo = T;
        if (csel < KOUT) {
          hi = T;
          T = (em - 2 > 0) ? ((unsigned)(em - 2) << 23) : 0u;
          attempt(T); lo = T;
          if (csel < KOUT) { hi = T; attempt(0u); lo = 0u; }
        }
      }
    }

    // ---- rare: binary refine until 64 <= count(>=lo) <= 128
    {
      unsigned csel_lo = csel, lastT = lo;
      while (csel_lo > CAND && lo + 1u < hi) {
        unsigned mid = lo + ((hi - lo) >> 1);
        attempt(mid); lastT = mid;
        if (csel >= KOUT) { lo = mid; csel_lo = csel; } else hi = mid;
      }
      if (lastT != lo) attempt(lo);
    }

    // ---- ultra-rare: >128 ties at lo: keep all > lo + smallest-index ties
    if (csel > CAND) {
      unsigned kgt = 0u;
#pragma unroll
      for (int j = 31; j >= 0; --j) kgt = (kgt << 1) | (unsigned)(bits[j] >= hi);
      unsigned slgt = __popc(kgt), incgt = slgt;
      SCAN_ADD_U(incgt);
      unsigned cgt = RDL(incgt, 63);
      unsigned cap = CAND - cgt;
      keep = kgt;
      unsigned run = 0u;
#pragma unroll
      for (int t = 0; t < 8; ++t) {
        unsigned f = 0u;
#pragma unroll
        for (int c = 3; c >= 0; --c) f = (f << 1) | (unsigned)(bits[4 * t + c] == lo);
        unsigned tc = __popc(f), it = tc;
        SCAN_ADD_U(it);
        unsigned tbase = run + it - tc;
#pragma unroll
        for (int c = 0; c < 4; ++c) {
          if (f & (1u << c)) {
            if (tbase < cap) keep |= 1u << (4 * t + c);
            ++tbase;
          }
        }
        run += RDL(it, 63);
      }
      sl = __popc(keep);
      inc = sl;
      SCAN_ADD_U(inc);
      csel = RDL(inc, 63);
    }

    // ---- compaction: DPP-scanned base + popc-indexed independent stores
    unsigned base = inc - sl;  // exclusive prefix = write base
#pragma unroll
    for (int j = 0; j < 32; ++j) {
      if (keep & (1u << j)) {
        unsigned pj = base + (unsigned)__popc(keep & ((1u << j) - 1u));
        cw[pj] = ((u64)bits[j] << 32) |
                 (u64)(lobase - (unsigned)((j >> 2) * 256 + (j & 3)));
      }
    }

    // ---- sort: k0 desc + k1 asc (21 dual stages), local exchange, merge top half
    u64 k0 = cw[lane];
    u64 k1 = cw[lane + 64u];
    // k=2
    STEP_A_D(0xB1, !(b2 ^ b1));
    // k=4
    STEP_A_D(0x4E, !(b4 ^ b2)); STEP_A_D(0xB1, !(b4 ^ b1));
    // k=8
    STEP_A_S(4, !(b8 ^ b4)); STEP_A_D(0x4E, !(b8 ^ b2)); STEP_A_D(0xB1, !(b8 ^ b1));
    // k=16
    STEP_A_S(8, !(b16 ^ b8)); STEP_A_S(4, !(b16 ^ b4));
    STEP_A_D(0x4E, !(b16 ^ b2)); STEP_A_D(0xB1, !(b16 ^ b1));
    // k=32
    STEP_A_S(16, !(b32 ^ b16)); STEP_A_S(8, !(b32 ^ b8)); STEP_A_S(4, !(b32 ^ b4));
    STEP_A_D(0x4E, !(b32 ^ b2)); STEP_A_D(0xB1, !(b32 ^ b1));
    // k=64 (lane&64 == 0 always)
    STEP_A_W(!b32);
    STEP_A_S(16, !b16); STEP_A_S(8, !b8); STEP_A_S(4, !b4);
    STEP_A_D(0x4E, !b2); STEP_A_D(0xB1, !b1);

    u64 av = k0 >= k1 ? k0 : k1;  // bitonic; holds the top-64 set
    STEP_B_W(!b32);
    STEP_B_S(16, !b16); STEP_B_S(8, !b8); STEP_B_S(4, !b4);
    STEP_B_D(0x4E, !b2); STEP_B_D(0xB1, !b1);

    // ---- per-sample k
    const unsigned n = row / (unsigned)Q;
    int kk = looks64 ? topk[2 * (int)n] : topk[(int)n];
    kk = kk > M_COLS ? M_COLS : (kk < 0 ? 0 : kk);

    // ---- softmax over first kk entries; lane = rank (sorted desc)
    float val = __uint_as_float((unsigned)(av >> 32));
    unsigned midx = 2047u - (unsigned)(av & 0xffffffffull);
    bool valid = (int)lane < kk;

    float vmx = __uint_as_float(
        (unsigned)__builtin_amdgcn_readfirstlane((int)(unsigned)(av >> 32)));
    float e = valid ? __expf(val - vmx) : 0.0f;
    float s = e;
    SCAN_ADD_F(s);
    float stot = __uint_as_float(RDL(__float_as_uint(s), 63));
    float w = valid ? (e / stot) : 0.0f;

    size_t o = (size_t)row * KOUT + lane;
    out_w[o] = w;
    out_i[o] = valid ? (float)midx : 0.0f;
  }
}

extern "C" void kernel_launch(void* const* d_in, const int* in_sizes, int n_in,
                              void* d_out, int out_size, void* d_ws, size_t ws_size,
                              hipStream_t stream) {
  const float* A = (const float*)d_in[0];
  const int* topk = (const int*)d_in[1];
  float* out = (float*)d_out;
  const int NQ = in_sizes[0] / M_COLS;
  const int N = in_sizes[1] > 0 ? in_sizes[1] : 1;
  const int Q = NQ / N;
  float* out_w = out;
  float* out_i = out + (size_t)NQ * KOUT;
  const int rows_per_block = 4 * ROWS;  // 4 waves x ROWS rows
  const int blocks = (NQ + rows_per_block - 1) / rows_per_block;
  hipLaunchKernelGGL(topk_route_kernel, dim3(blocks), dim3(BLK), 0, stream, A,
                     topk, out_w, out_i, NQ, Q, N);
}

// Round 8
// 31.133 us; speedup vs baseline: 4.3272x; 1.2712x over previous
//
#include <hip/hip_runtime.h>

#define M_COLS 2048
#define KOUT 64
#define CAND 128
#define BLK 256  // 4 waves/block, 1 row/wave

typedef unsigned long long u64;

// ---- DPP move (pure VALU): quad_perm / row_shl / row_shr / row_bcast
#define DPPU(old, src, ctrl, rmask) \
  ((unsigned)__builtin_amdgcn_update_dpp((int)(old), (int)(src), (ctrl), (rmask), 0xF, false))
#define RDL(x, l) ((unsigned)__builtin_amdgcn_readlane((int)(x), (l)))

// canonical wave64 inclusive scans: row_shr 1/2/4/8, bcast15 (rows 1,3), bcast31 (rows 2,3)
#define SCAN_ADD_U(x)             \
  do {                            \
    x += DPPU(0u, x, 0x111, 0xF); \
    x += DPPU(0u, x, 0x112, 0xF); \
    x += DPPU(0u, x, 0x114, 0xF); \
    x += DPPU(0u, x, 0x118, 0xF); \
    x += DPPU(0u, x, 0x142, 0xA); \
    x += DPPU(0u, x, 0x143, 0xC); \
  } while (0)

#define SCAN_MAX_U(x)                                  \
  do {                                                 \
    unsigned _t;                                       \
    _t = DPPU(0u, x, 0x111, 0xF); x = x > _t ? x : _t; \
    _t = DPPU(0u, x, 0x112, 0xF); x = x > _t ? x : _t; \
    _t = DPPU(0u, x, 0x114, 0xF); x = x > _t ? x : _t; \
    _t = DPPU(0u, x, 0x118, 0xF); x = x > _t ? x : _t; \
    _t = DPPU(0u, x, 0x142, 0xA); x = x > _t ? x : _t; \
    _t = DPPU(0u, x, 0x143, 0xC); x = x > _t ? x : _t; \
  } while (0)

#define SCAN_ADD_F(x)                                               \
  do {                                                              \
    x += __uint_as_float(DPPU(0u, __float_as_uint(x), 0x111, 0xF)); \
    x += __uint_as_float(DPPU(0u, __float_as_uint(x), 0x112, 0xF)); \
    x += __uint_as_float(DPPU(0u, __float_as_uint(x), 0x114, 0xF)); \
    x += __uint_as_float(DPPU(0u, __float_as_uint(x), 0x118, 0xF)); \
    x += __uint_as_float(DPPU(0u, __float_as_uint(x), 0x142, 0xA)); \
    x += __uint_as_float(DPPU(0u, __float_as_uint(x), 0x143, 0xC)); \
  } while (0)

// xor-lane exchange within 32-lane halves via ds_swizzle (BitMode: (xor<<10)|0x1f)
#define SWZ(v, J) ((unsigned)__builtin_amdgcn_ds_swizzle((int)(v), (((J) << 10) | 0x1f)))

// u64 partner fetch, ds_swizzle path (J=16 only now)
#define EX_S(dst, src, J)                           \
  do {                                              \
    unsigned _lo = SWZ((unsigned)(src), J);         \
    unsigned _hi = SWZ((unsigned)((src) >> 32), J); \
    dst = ((u64)_hi << 32) | _lo;                   \
  } while (0)
// u64 partner fetch, quad_perm DPP (xor1 = 0xB1, xor2 = 0x4E)
#define EX_D(dst, src, CTRL)                                     \
  do {                                                           \
    unsigned _lo = DPPU(0u, (unsigned)(src), CTRL, 0xF);         \
    unsigned _hi = DPPU(0u, (unsigned)((src) >> 32), CTRL, 0xF); \
    dst = ((u64)_hi << 32) | _lo;                                \
  } while (0)
// u64 partner fetch, xor4/xor8 via row_shl/row_shr DPP pair + select
//   xor4: partner = (lane&4) ? lane-4 (row_shr:4) : lane+4 (row_shl:4)
//   xor8: partner = (lane&8) ? lane-8 (row_shr:8) : lane+8 (row_shl:8)
#define EX_P(dst, src, CU, CD, SEL)                       \
  do {                                                    \
    unsigned _lu = DPPU(0u, (unsigned)(src), CU, 0xF);    \
    unsigned _ld = DPPU(0u, (unsigned)(src), CD, 0xF);    \
    unsigned _hu = DPPU(0u, (unsigned)((src) >> 32), CU, 0xF); \
    unsigned _hd = DPPU(0u, (unsigned)((src) >> 32), CD, 0xF); \
    unsigned _lo = (SEL) ? _ld : _lu;                     \
    unsigned _hi = (SEL) ? _hd : _hu;                     \
    dst = ((u64)_hi << 32) | _lo;                         \
  } while (0)
// xor32 via bpermute-backed shfl
#define EX_W(dst, src)                                                         \
  do {                                                                         \
    unsigned _lo = (unsigned)__shfl_xor((int)(unsigned)(src), 32, 64);         \
    unsigned _hi = (unsigned)__shfl_xor((int)(unsigned)((src) >> 32), 32, 64); \
    dst = ((u64)_hi << 32) | _lo;                                              \
  } while (0)

// dual compare-exchange: k0 descending, k1 ascending (mirrored)
#define CMPSEL(up)                       \
  do {                                   \
    k0 = ((k0 >= o0) == (up)) ? k0 : o0; \
    k1 = ((k1 >= o1) == (up)) ? o1 : k1; \
  } while (0)

#define STEP_A_S(J, UP) do { u64 o0, o1; EX_S(o0, k0, J); EX_S(o1, k1, J); CMPSEL(UP); } while (0)
#define STEP_A_D(CTRL, UP) do { u64 o0, o1; EX_D(o0, k0, CTRL); EX_D(o1, k1, CTRL); CMPSEL(UP); } while (0)
#define STEP_A_P(CU, CD, SEL, UP) \
  do { u64 o0, o1; EX_P(o0, k0, CU, CD, SEL); EX_P(o1, k1, CU, CD, SEL); CMPSEL(UP); } while (0)
#define STEP_A_W(UP) do { u64 o0, o1; EX_W(o0, k0); EX_W(o1, k1); CMPSEL(UP); } while (0)

// descending bitonic merge stage on av
#define STEP_B_S(J, UP) do { u64 o; EX_S(o, av, J); av = ((av >= o) == (UP)) ? av : o; } while (0)
#define STEP_B_D(CTRL, UP) do { u64 o; EX_D(o, av, CTRL); av = ((av >= o) == (UP)) ? av : o; } while (0)
#define STEP_B_P(CU, CD, SEL, UP) \
  do { u64 o; EX_P(o, av, CU, CD, SEL); av = ((av >= o) == (UP)) ? av : o; } while (0)
#define STEP_B_W(UP) do { u64 o; EX_W(o, av); av = ((av >= o) == (UP)) ? av : o; } while (0)

__global__ __launch_bounds__(BLK) void topk_route_kernel(
    const float* __restrict__ A, const int* __restrict__ topk,
    float* __restrict__ out_w, float* __restrict__ out_i, int NQ, int Q, int N) {
  __shared__ u64 cand[4][CAND];

  const unsigned tid = threadIdx.x;
  const unsigned wv = tid >> 6, lane = tid & 63u;
  const unsigned row = blockIdx.x * 4u + wv;
  if ((int)row >= NQ) return;
  const unsigned n = row / (unsigned)Q;

  // ---- load + mask fused (8x float4, coalesced within the wave)
  const float4* a4 = (const float4*)(A + (size_t)row * M_COLS);
  unsigned bits[32];
#pragma unroll
  for (int t = 0; t < 8; ++t) {
    float4 vv = a4[lane + 64u * (unsigned)t];
    bits[4 * t + 0] = __float_as_uint(vv.x) & 0x7fffffffu;
    bits[4 * t + 1] = __float_as_uint(vv.y) & 0x7fffffffu;
    bits[4 * t + 2] = __float_as_uint(vv.z) & 0x7fffffffu;
    bits[4 * t + 3] = __float_as_uint(vv.w) & 0x7fffffffu;
  }

  // zero pad slots of the upper half (lower 64 always overwritten: csel >= 64)
  cand[wv][lane + 64u] = 0ull;

  // ---- branch-free topk sniff (int64 vs int32 layout; uniform)
  int kk;
  if (N >= 8) {
    const int4* t4 = (const int4*)topk;
    int4 a = t4[0], b = t4[1], c = t4[2], d = t4[3];
    int k64 = topk[2 * (int)n], k32 = topk[(int)n];
    bool looks64 = (a.y == 0) & (a.w == 0) & (b.y == 0) & (b.w == 0) &
                   (c.y == 0) & (c.w == 0) & (d.y == 0) & (d.w == 0) &
                   (a.x >= 1) & (a.z >= 1) & (b.x >= 1) & (b.z >= 1) &
                   (c.x >= 1) & (c.z >= 1) & (d.x >= 1) & (d.z >= 1);
    kk = looks64 ? k64 : k32;
  } else {
    bool looks64 = true;
    for (int i = 0; i < N; ++i) {
      int l = topk[2 * i], h = topk[2 * i + 1];
      if (h != 0 || l < 1) { looks64 = false; break; }
    }
    kk = looks64 ? topk[2 * (int)n] : topk[(int)n];
  }
  kk = kk > M_COLS ? M_COLS : (kk < 0 ? 0 : kk);

  // ---- wave max -> uniform em
  unsigned mx = bits[0];
#pragma unroll
  for (int j = 1; j < 32; ++j) mx = bits[j] > mx ? bits[j] : mx;
  SCAN_MAX_U(mx);
  mx = RDL(mx, 63);
  const int em = (int)(mx >> 23);

  // attempt(T): keep-mask (4 independent 8-chains) + popc + DPP scan + total
  unsigned keep = 0u, sl = 0u, inc = 0u, csel = 0u;
  auto attempt = [&](unsigned T) {
    unsigned q0 = 0u, q1 = 0u, q2 = 0u, q3 = 0u;
#pragma unroll
    for (int j = 7; j >= 0; --j) {
      q0 = q0 + q0 + (unsigned)(bits[j] >= T);
      q1 = q1 + q1 + (unsigned)(bits[8 + j] >= T);
      q2 = q2 + q2 + (unsigned)(bits[16 + j] >= T);
      q3 = q3 + q3 + (unsigned)(bits[24 + j] >= T);
    }
    keep = q0 | (q1 << 8) | (q2 << 16) | (q3 << 24);
    sl = __popc(keep);
    inc = sl;
    SCAN_ADD_U(inc);
    csel = RDL(inc, 63);
  };

  // ---- probe em, em-1, em-2 (T=0 always qualifies: count=2048)
  unsigned lo, hi = mx + 1u;
  {
    unsigned T = (em > 0) ? ((unsigned)em << 23) : 0u;
    attempt(T); lo = T;
    if (csel < KOUT) {
      hi = T;
      T = (em - 1 > 0) ? ((unsigned)(em - 1) << 23) : 0u;
      attempt(T); lo = T;
      if (csel < KOUT) {
        hi = T;
        T = (em - 2 > 0) ? ((unsigned)(em - 2) << 23) : 0u;
        attempt(T); lo = T;
        if (csel < KOUT) { hi = T; attempt(0u); lo = 0u; }
      }
    }
  }

  // ---- rare: binary refine until 64 <= count(>=lo) <= 128
  {
    unsigned csel_lo = csel, lastT = lo;
    while (csel_lo > CAND && lo + 1u < hi) {
      unsigned mid = lo + ((hi - lo) >> 1);
      attempt(mid); lastT = mid;
      if (csel >= KOUT) { lo = mid; csel_lo = csel; } else hi = mid;
    }
    if (lastT != lo) attempt(lo);
  }

  // ---- ultra-rare: >128 ties at lo: keep all > lo + smallest-index ties
  if (csel > CAND) {
    unsigned kgt = 0u;
#pragma unroll
    for (int j = 31; j >= 0; --j) kgt = (kgt << 1) | (unsigned)(bits[j] >= hi);
    unsigned slgt = __popc(kgt), incgt = slgt;
    SCAN_ADD_U(incgt);
    unsigned cgt = RDL(incgt, 63);
    unsigned cap = CAND - cgt;
    keep = kgt;
    unsigned run = 0u;
#pragma unroll
    for (int t = 0; t < 8; ++t) {
      unsigned f = 0u;
#pragma unroll
      for (int c = 3; c >= 0; --c) f = (f << 1) | (unsigned)(bits[4 * t + c] == lo);
      unsigned tc = __popc(f), it = tc;
      SCAN_ADD_U(it);
      unsigned tbase = run + it - tc;
#pragma unroll
      for (int c = 0; c < 4; ++c) {
        if (f & (1u << c)) {
          if (tbase < cap) keep |= 1u << (4 * t + c);
          ++tbase;
        }
      }
      run += RDL(it, 63);
    }
    sl = __popc(keep);
    inc = sl;
    SCAN_ADD_U(inc);
    csel = RDL(inc, 63);
  }

  // ---- compaction: DPP-scanned base + popc-indexed independent stores
  unsigned base = inc - sl;  // exclusive prefix = write base
  const unsigned lobase = 2047u - 4u * lane;
  u64* cw = &cand[wv][0];
#pragma unroll
  for (int j = 0; j < 32; ++j) {
    if (keep & (1u << j)) {
      unsigned pj = base + (unsigned)__popc(keep & ((1u << j) - 1u));
      cw[pj] = ((u64)bits[j] << 32) |
               (u64)(lobase - (unsigned)((j >> 2) * 256 + (j & 3)));
    }
  }

  // ---- per-stage comparator flags from lane bits
  const bool b1 = (lane & 1u) != 0u, b2 = (lane & 2u) != 0u, b4 = (lane & 4u) != 0u;
  const bool b8 = (lane & 8u) != 0u, b16 = (lane & 16u) != 0u, b32 = (lane & 32u) != 0u;

  // ---- sort: k0 desc + k1 asc (21 dual stages), local exchange, merge top half
  // xor1/xor2 = quad_perm DPP; xor4/xor8 = row_shl/shr DPP pair; xor16 = swizzle;
  // xor32 = bpermute. Only 5 stages remain on the LDS pipe.
  u64 k0 = cw[lane];
  u64 k1 = cw[lane + 64u];
  // k=2
  STEP_A_D(0xB1, !(b2 ^ b1));
  // k=4
  STEP_A_D(0x4E, !(b4 ^ b2)); STEP_A_D(0xB1, !(b4 ^ b1));
  // k=8
  STEP_A_P(0x104, 0x114, b4, !(b8 ^ b4));
  STEP_A_D(0x4E, !(b8 ^ b2)); STEP_A_D(0xB1, !(b8 ^ b1));
  // k=16
  STEP_A_P(0x108, 0x118, b8, !(b16 ^ b8));
  STEP_A_P(0x104, 0x114, b4, !(b16 ^ b4));
  STEP_A_D(0x4E, !(b16 ^ b2)); STEP_A_D(0xB1, !(b16 ^ b1));
  // k=32
  STEP_A_S(16, !(b32 ^ b16));
  STEP_A_P(0x108, 0x118, b8, !(b32 ^ b8));
  STEP_A_P(0x104, 0x114, b4, !(b32 ^ b4));
  STEP_A_D(0x4E, !(b32 ^ b2)); STEP_A_D(0xB1, !(b32 ^ b1));
  // k=64 (lane&64 == 0 always)
  STEP_A_W(!b32);
  STEP_A_S(16, !b16);
  STEP_A_P(0x108, 0x118, b8, !b8);
  STEP_A_P(0x104, 0x114, b4, !b4);
  STEP_A_D(0x4E, !b2); STEP_A_D(0xB1, !b1);

  u64 av = k0 >= k1 ? k0 : k1;  // bitonic; holds the top-64 set
  STEP_B_W(!b32);
  STEP_B_S(16, !b16);
  STEP_B_P(0x108, 0x118, b8, !b8);
  STEP_B_P(0x104, 0x114, b4, !b4);
  STEP_B_D(0x4E, !b2); STEP_B_D(0xB1, !b1);

  // ---- softmax over first kk entries; lane = rank (sorted desc)
  float val = __uint_as_float((unsigned)(av >> 32));
  unsigned midx = 2047u - (unsigned)(av & 0xffffffffull);
  bool valid = (int)lane < kk;

  float vmx = __uint_as_float(
      (unsigned)__builtin_amdgcn_readfirstlane((int)(unsigned)(av >> 32)));
  float e = valid ? __expf(val - vmx) : 0.0f;
  float s = e;
  SCAN_ADD_F(s);
  float stot = __uint_as_float(RDL(__float_as_uint(s), 63));
  float w = valid ? (e / stot) : 0.0f;

  size_t o = (size_t)row * KOUT + lane;
  out_w[o] = w;
  out_i[o] = valid ? (float)midx : 0.0f;
}

extern "C" void kernel_launch(void* const* d_in, const int* in_sizes, int n_in,
                              void* d_out, int out_size, void* d_ws, size_t ws_size,
                              hipStream_t stream) {
  const float* A = (const float*)d_in[0];
  const int* topk = (const int*)d_in[1];
  float* out = (float*)d_out;
  const int NQ = in_sizes[0] / M_COLS;
  const int N = in_sizes[1] > 0 ? in_sizes[1] : 1;
  const int Q = NQ / N;
  float* out_w = out;
  float* out_i = out + (size_t)NQ * KOUT;
  const int blocks = (NQ + 3) / 4;
  hipLaunchKernelGGL(topk_route_kernel, dim3(blocks), dim3(BLK), 0, stream, A,
                     topk, out_w, out_i, NQ, Q, N);
}

// Round 9
// 29.782 us; speedup vs baseline: 4.5235x; 1.0454x over previous
//
#include <hip/hip_runtime.h>

#define M_COLS 2048
#define KOUT 64
#define CAND 128
#define BLK 256  // 4 waves/block, 1 row/wave

typedef unsigned long long u64;

// ---- DPP move (pure VALU): quad_perm / row_shr / row_bcast
#define DPPU(old, src, ctrl, rmask) \
  ((unsigned)__builtin_amdgcn_update_dpp((int)(old), (int)(src), (ctrl), (rmask), 0xF, false))
#define RDL(x, l) ((unsigned)__builtin_amdgcn_readlane((int)(x), (l)))

// canonical wave64 inclusive scans: row_shr 1/2/4/8, bcast15 (rows 1,3), bcast31 (rows 2,3)
#define SCAN_ADD_U(x)             \
  do {                            \
    x += DPPU(0u, x, 0x111, 0xF); \
    x += DPPU(0u, x, 0x112, 0xF); \
    x += DPPU(0u, x, 0x114, 0xF); \
    x += DPPU(0u, x, 0x118, 0xF); \
    x += DPPU(0u, x, 0x142, 0xA); \
    x += DPPU(0u, x, 0x143, 0xC); \
  } while (0)

#define SCAN_MAX_U(x)                                  \
  do {                                                 \
    unsigned _t;                                       \
    _t = DPPU(0u, x, 0x111, 0xF); x = x > _t ? x : _t; \
    _t = DPPU(0u, x, 0x112, 0xF); x = x > _t ? x : _t; \
    _t = DPPU(0u, x, 0x114, 0xF); x = x > _t ? x : _t; \
    _t = DPPU(0u, x, 0x118, 0xF); x = x > _t ? x : _t; \
    _t = DPPU(0u, x, 0x142, 0xA); x = x > _t ? x : _t; \
    _t = DPPU(0u, x, 0x143, 0xC); x = x > _t ? x : _t; \
  } while (0)

#define SCAN_ADD_F(x)                                               \
  do {                                                              \
    x += __uint_as_float(DPPU(0u, __float_as_uint(x), 0x111, 0xF)); \
    x += __uint_as_float(DPPU(0u, __float_as_uint(x), 0x112, 0xF)); \
    x += __uint_as_float(DPPU(0u, __float_as_uint(x), 0x114, 0xF)); \
    x += __uint_as_float(DPPU(0u, __float_as_uint(x), 0x118, 0xF)); \
    x += __uint_as_float(DPPU(0u, __float_as_uint(x), 0x142, 0xA)); \
    x += __uint_as_float(DPPU(0u, __float_as_uint(x), 0x143, 0xC)); \
  } while (0)

// xor-lane exchange within 32-lane halves via ds_swizzle (BitMode: (xor<<10)|0x1f)
#define SWZ(v, J) ((unsigned)__builtin_amdgcn_ds_swizzle((int)(v), (((J) << 10) | 0x1f)))

// u64 partner fetch: ds_swizzle (J=4,8,16), quad_perm DPP (xor1=0xB1, xor2=0x4E), bpermute (32)
#define EX_S(dst, src, J)                           \
  do {                                              \
    unsigned _lo = SWZ((unsigned)(src), J);         \
    unsigned _hi = SWZ((unsigned)((src) >> 32), J); \
    dst = ((u64)_hi << 32) | _lo;                   \
  } while (0)
#define EX_D(dst, src, CTRL)                                     \
  do {                                                           \
    unsigned _lo = DPPU(0u, (unsigned)(src), CTRL, 0xF);         \
    unsigned _hi = DPPU(0u, (unsigned)((src) >> 32), CTRL, 0xF); \
    dst = ((u64)_hi << 32) | _lo;                                \
  } while (0)
#define EX_W(dst, src)                                                         \
  do {                                                                         \
    unsigned _lo = (unsigned)__shfl_xor((int)(unsigned)(src), 32, 64);         \
    unsigned _hi = (unsigned)__shfl_xor((int)(unsigned)((src) >> 32), 32, 64); \
    dst = ((u64)_hi << 32) | _lo;                                              \
  } while (0)

// dual compare-exchange: k0 descending, k1 ascending (mirrored)
#define CMPSEL(up)                       \
  do {                                   \
    k0 = ((k0 >= o0) == (up)) ? k0 : o0; \
    k1 = ((k1 >= o1) == (up)) ? o1 : k1; \
  } while (0)

#define STEP_A_S(J, UP) do { u64 o0, o1; EX_S(o0, k0, J); EX_S(o1, k1, J); CMPSEL(UP); } while (0)
#define STEP_A_D(CTRL, UP) do { u64 o0, o1; EX_D(o0, k0, CTRL); EX_D(o1, k1, CTRL); CMPSEL(UP); } while (0)
#define STEP_A_W(UP) do { u64 o0, o1; EX_W(o0, k0); EX_W(o1, k1); CMPSEL(UP); } while (0)

// descending bitonic merge stage on av
#define STEP_B_S(J, UP) do { u64 o; EX_S(o, av, J); av = ((av >= o) == (UP)) ? av : o; } while (0)
#define STEP_B_D(CTRL, UP) do { u64 o; EX_D(o, av, CTRL); av = ((av >= o) == (UP)) ? av : o; } while (0)
#define STEP_B_W(UP) do { u64 o; EX_W(o, av); av = ((av >= o) == (UP)) ? av : o; } while (0)

__global__ __launch_bounds__(BLK) void topk_route_kernel(
    const float* __restrict__ A, const int* __restrict__ topk,
    float* __restrict__ out_w, float* __restrict__ out_i, int NQ, int Q, int N) {
  __shared__ u64 cand[4][CAND];

  const unsigned tid = threadIdx.x;
  const unsigned wv = tid >> 6, lane = tid & 63u;
  const unsigned row = blockIdx.x * 4u + wv;
  if ((int)row >= NQ) return;
  const unsigned n = row / (unsigned)Q;

  // ---- load + mask fused (8x float4, coalesced within the wave)
  const float4* a4 = (const float4*)(A + (size_t)row * M_COLS);
  unsigned bits[32];
#pragma unroll
  for (int t = 0; t < 8; ++t) {
    float4 vv = a4[lane + 64u * (unsigned)t];
    bits[4 * t + 0] = __float_as_uint(vv.x) & 0x7fffffffu;
    bits[4 * t + 1] = __float_as_uint(vv.y) & 0x7fffffffu;
    bits[4 * t + 2] = __float_as_uint(vv.z) & 0x7fffffffu;
    bits[4 * t + 3] = __float_as_uint(vv.w) & 0x7fffffffu;
  }

  // zero pad slots of the upper half (lower 64 always overwritten: csel >= 64)
  cand[wv][lane + 64u] = 0ull;

  // ---- branch-free topk sniff (int64 vs int32 layout; uniform)
  int kk;
  if (N >= 8) {
    const int4* t4 = (const int4*)topk;
    int4 a = t4[0], b = t4[1], c = t4[2], d = t4[3];
    int k64 = topk[2 * (int)n], k32 = topk[(int)n];
    bool looks64 = (a.y == 0) & (a.w == 0) & (b.y == 0) & (b.w == 0) &
                   (c.y == 0) & (c.w == 0) & (d.y == 0) & (d.w == 0) &
                   (a.x >= 1) & (a.z >= 1) & (b.x >= 1) & (b.z >= 1) &
                   (c.x >= 1) & (c.z >= 1) & (d.x >= 1) & (d.z >= 1);
    kk = looks64 ? k64 : k32;
  } else {
    bool looks64 = true;
    for (int i = 0; i < N; ++i) {
      int l = topk[2 * i], h = topk[2 * i + 1];
      if (h != 0 || l < 1) { looks64 = false; break; }
    }
    kk = looks64 ? topk[2 * (int)n] : topk[(int)n];
  }
  kk = kk > M_COLS ? M_COLS : (kk < 0 ? 0 : kk);

  // attempt(T): keep-mask (4 independent 8-chains) + popc + DPP scan + total
  unsigned keep = 0u, sl = 0u, inc = 0u, csel = 0u;
  auto attempt = [&](unsigned T) {
    unsigned q0 = 0u, q1 = 0u, q2 = 0u, q3 = 0u;
#pragma unroll
    for (int j = 7; j >= 0; --j) {
      q0 = q0 + q0 + (unsigned)(bits[j] >= T);
      q1 = q1 + q1 + (unsigned)(bits[8 + j] >= T);
      q2 = q2 + q2 + (unsigned)(bits[16 + j] >= T);
      q3 = q3 + q3 + (unsigned)(bits[24 + j] >= T);
    }
    keep = q0 | (q1 << 8) | (q2 << 16) | (q3 << 24);
    sl = __popc(keep);
    inc = sl;
    SCAN_ADD_U(inc);
    csel = RDL(inc, 63);
  };

  // ---- FAST PATH: single fixed probe at |x| >= 2.0 (N(0,1): count ~93 in [64,128])
  attempt(0x40000000u);

  if (csel < KOUT || csel > CAND) {
    // ---- SLOW PATH (any-data exact): wave max -> em cascade -> refine -> ties
    unsigned mx = bits[0];
#pragma unroll
    for (int j = 1; j < 32; ++j) mx = bits[j] > mx ? bits[j] : mx;
    SCAN_MAX_U(mx);
    mx = RDL(mx, 63);
    const int em = (int)(mx >> 23);

    unsigned lo, hi = mx + 1u;
    {
      unsigned T = (em > 0) ? ((unsigned)em << 23) : 0u;
      attempt(T); lo = T;
      if (csel < KOUT) {
        hi = T;
        T = (em - 1 > 0) ? ((unsigned)(em - 1) << 23) : 0u;
        attempt(T); lo = T;
        if (csel < KOUT) {
          hi = T;
          T = (em - 2 > 0) ? ((unsigned)(em - 2) << 23) : 0u;
          attempt(T); lo = T;
          if (csel < KOUT) { hi = T; attempt(0u); lo = 0u; }
        }
      }
    }

    // binary refine until 64 <= count(>=lo) <= 128
    {
      unsigned csel_lo = csel, lastT = lo;
      while (csel_lo > CAND && lo + 1u < hi) {
        unsigned mid = lo + ((hi - lo) >> 1);
        attempt(mid); lastT = mid;
        if (csel >= KOUT) { lo = mid; csel_lo = csel; } else hi = mid;
      }
      if (lastT != lo) attempt(lo);
    }

    // ultra-rare: >128 ties at lo: keep all > lo + smallest-index ties
    if (csel > CAND) {
      unsigned kgt = 0u;
#pragma unroll
      for (int j = 31; j >= 0; --j) kgt = (kgt << 1) | (unsigned)(bits[j] >= hi);
      unsigned slgt = __popc(kgt), incgt = slgt;
      SCAN_ADD_U(incgt);
      unsigned cgt = RDL(incgt, 63);
      unsigned cap = CAND - cgt;
      keep = kgt;
      unsigned run = 0u;
#pragma unroll
      for (int t = 0; t < 8; ++t) {
        unsigned f = 0u;
#pragma unroll
        for (int c = 3; c >= 0; --c) f = (f << 1) | (unsigned)(bits[4 * t + c] == lo);
        unsigned tc = __popc(f), it = tc;
        SCAN_ADD_U(it);
        unsigned tbase = run + it - tc;
#pragma unroll
        for (int c = 0; c < 4; ++c) {
          if (f & (1u << c)) {
            if (tbase < cap) keep |= 1u << (4 * t + c);
            ++tbase;
          }
        }
        run += RDL(it, 63);
      }
      sl = __popc(keep);
      inc = sl;
      SCAN_ADD_U(inc);
      csel = RDL(inc, 63);
    }
  }

  // ---- compaction: DPP-scanned base + popc-indexed independent stores
  unsigned base = inc - sl;  // exclusive prefix = write base
  const unsigned lobase = 2047u - 4u * lane;
  u64* cw = &cand[wv][0];
#pragma unroll
  for (int j = 0; j < 32; ++j) {
    if (keep & (1u << j)) {
      unsigned pj = base + (unsigned)__popc(keep & ((1u << j) - 1u));
      cw[pj] = ((u64)bits[j] << 32) |
               (u64)(lobase - (unsigned)((j >> 2) * 256 + (j & 3)));
    }
  }

  // ---- per-stage comparator flags from lane bits
  const bool b1 = (lane & 1u) != 0u, b2 = (lane & 2u) != 0u, b4 = (lane & 4u) != 0u;
  const bool b8 = (lane & 8u) != 0u, b16 = (lane & 16u) != 0u, b32 = (lane & 32u) != 0u;

  // ---- sort: k0 desc + k1 asc (21 dual stages), local exchange, merge top half
  u64 k0 = cw[lane];
  u64 k1 = cw[lane + 64u];
  // k=2
  STEP_A_D(0xB1, !(b2 ^ b1));
  // k=4
  STEP_A_D(0x4E, !(b4 ^ b2)); STEP_A_D(0xB1, !(b4 ^ b1));
  // k=8
  STEP_A_S(4, !(b8 ^ b4)); STEP_A_D(0x4E, !(b8 ^ b2)); STEP_A_D(0xB1, !(b8 ^ b1));
  // k=16
  STEP_A_S(8, !(b16 ^ b8)); STEP_A_S(4, !(b16 ^ b4));
  STEP_A_D(0x4E, !(b16 ^ b2)); STEP_A_D(0xB1, !(b16 ^ b1));
  // k=32
  STEP_A_S(16, !(b32 ^ b16)); STEP_A_S(8, !(b32 ^ b8)); STEP_A_S(4, !(b32 ^ b4));
  STEP_A_D(0x4E, !(b32 ^ b2)); STEP_A_D(0xB1, !(b32 ^ b1));
  // k=64 (lane&64 == 0 always)
  STEP_A_W(!b32);
  STEP_A_S(16, !b16); STEP_A_S(8, !b8); STEP_A_S(4, !b4);
  STEP_A_D(0x4E, !b2); STEP_A_D(0xB1, !b1);

  u64 av = k0 >= k1 ? k0 : k1;  // bitonic; holds the top-64 set
  STEP_B_W(!b32);
  STEP_B_S(16, !b16); STEP_B_S(8, !b8); STEP_B_S(4, !b4);
  STEP_B_D(0x4E, !b2); STEP_B_D(0xB1, !b1);

  // ---- softmax over first kk entries; lane = rank (sorted desc)
  float val = __uint_as_float((unsigned)(av >> 32));
  unsigned midx = 2047u - (unsigned)(av & 0xffffffffull);
  bool valid = (int)lane < kk;

  float vmx = __uint_as_float(
      (unsigned)__builtin_amdgcn_readfirstlane((int)(unsigned)(av >> 32)));
  float e = valid ? __expf(val - vmx) : 0.0f;
  float s = e;
  SCAN_ADD_F(s);
  float stot = __uint_as_float(RDL(__float_as_uint(s), 63));
  float w = valid ? (e / stot) : 0.0f;

  size_t o = (size_t)row * KOUT + lane;
  out_w[o] = w;
  out_i[o] = valid ? (float)midx : 0.0f;
}

extern "C" void kernel_launch(void* const* d_in, const int* in_sizes, int n_in,
                              void* d_out, int out_size, void* d_ws, size_t ws_size,
                              hipStream_t stream) {
  const float* A = (const float*)d_in[0];
  const int* topk = (const int*)d_in[1];
  float* out = (float*)d_out;
  const int NQ = in_sizes[0] / M_COLS;
  const int N = in_sizes[1] > 0 ? in_sizes[1] : 1;
  const int Q = NQ / N;
  float* out_w = out;
  float* out_i = out + (size_t)NQ * KOUT;
  const int blocks = (NQ + 3) / 4;
  hipLaunchKernelGGL(topk_route_kernel, dim3(blocks), dim3(BLK), 0, stream, A,
                     topk, out_w, out_i, NQ, Q, N);
}